// Round 1
// baseline (727.104 us; speedup 1.0000x reference)
//
#include <hip/hip_runtime.h>
#include <stdint.h>

#define NPIX     65536
#define NTHREADS 1024
#define EPT      (NPIX / NTHREADS)   // 64
#define NSLICES  512
#define NFEAT    18
#define EMB      256
#define THRESH_RANK 52428u  // 0.8f*(65536-1) == 52428.0 exactly in f32 => fr == 0

// ---------- sortable key mapping (monotonic with float order) ----------
__device__ __forceinline__ uint32_t f2key(float f) {
  uint32_t u = __float_as_uint(f);
  return u ^ ((u & 0x80000000u) ? 0xFFFFFFFFu : 0x80000000u);
}
__device__ __forceinline__ float key2f(uint32_t k) {
  uint32_t u = (k & 0x80000000u) ? (k ^ 0x80000000u) : ~k;
  return __uint_as_float(u);
}

// smallest index b in [0,2048) with C[b] > r  (C = inclusive prefix)
__device__ __forceinline__ int findbin(const uint32_t* C, uint32_t r) {
  int lo = 0, hi = 2047;
  while (lo < hi) { int mid = (lo + hi) >> 1; if (C[mid] > r) hi = mid; else lo = mid + 1; }
  return lo;
}

// inclusive prefix sum over 2048 bins (1024 threads, 2 bins/thread); trailing barrier
__device__ void scan2048(const uint32_t* H, uint32_t* C, uint32_t* Wsum) {
  int tid = threadIdx.x, lane = tid & 63, wid = tid >> 6;
  uint32_t a1 = H[2 * tid + 1];
  uint32_t v = H[2 * tid] + a1;
  for (int d = 1; d < 64; d <<= 1) {
    uint32_t t = __shfl_up(v, d);
    if (lane >= d) v += t;
  }
  if (lane == 63) Wsum[wid] = v;
  __syncthreads();
  uint32_t woff = 0;
  for (int w = 0; w < wid; ++w) woff += Wsum[w];
  v += woff;
  C[2 * tid + 1] = v;
  C[2 * tid]     = v - a1;
  __syncthreads();
}

// level-2 histogram pass: bins (key>>10)&2047 for elements with (key>>21)==b1
__device__ void histpass2(const float* sl, int b1, uint32_t* H2) {
  int tid = threadIdx.x;
  H2[2 * tid] = 0; H2[2 * tid + 1] = 0;
  __syncthreads();
#pragma unroll 8
  for (int t = 0; t < EPT; ++t) {
    uint32_t k = f2key(sl[tid + t * NTHREADS]);
    if ((int)(k >> 21) == b1) atomicAdd(&H2[(k >> 10) & 2047u], 1u);
  }
  __syncthreads();
}

// level-3 histogram pass: bins key&1023 for elements with (key>>10)==pfx
__device__ void histpass3(const float* sl, uint32_t pfx, uint32_t* H2) {
  int tid = threadIdx.x;
  H2[2 * tid] = 0; H2[2 * tid + 1] = 0;
  __syncthreads();
#pragma unroll 8
  for (int t = 0; t < EPT; ++t) {
    uint32_t k = f2key(sl[tid + t * NTHREADS]);
    if ((k >> 10) == pfx) atomicAdd(&H2[k & 1023u], 1u);
  }
  __syncthreads();
}

// single-rank select, also returns count of elements strictly below the value
__device__ float select_rank_cnt(const float* sl, uint32_t rank, const uint32_t* C1,
                                 uint32_t* H2, uint32_t* C2, uint32_t* Wsum,
                                 uint32_t* cnt_lt) {
  int b1 = findbin(C1, rank);
  uint32_t bel1 = b1 ? C1[b1 - 1] : 0u;
  uint32_t r1 = rank - bel1;
  histpass2(sl, b1, H2); scan2048(H2, C2, Wsum);
  int b2 = findbin(C2, r1);
  uint32_t bel2 = b2 ? C2[b2 - 1] : 0u;
  uint32_t r2 = r1 - bel2;
  histpass3(sl, ((uint32_t)b1 << 11) | (uint32_t)b2, H2); scan2048(H2, C2, Wsum);
  int b3 = findbin(C2, r2);
  uint32_t bel3 = b3 ? C2[b3 - 1] : 0u;
  *cnt_lt = bel1 + bel2 + bel3;
  return key2f(((uint32_t)b1 << 21) | ((uint32_t)b2 << 10) | (uint32_t)b3);
}

// select ranks ra and rb (rb = ra+1) sharing passes when they fall in the same bins
__device__ void select_pair(const float* sl, uint32_t ra, uint32_t rb, int needB,
                            const uint32_t* C1, uint32_t* H2, uint32_t* C2, uint32_t* Wsum,
                            float* vA, float* vB) {
  int b1a = findbin(C1, ra);
  uint32_t bel1a = b1a ? C1[b1a - 1] : 0u;
  uint32_t r1a = ra - bel1a;
  histpass2(sl, b1a, H2); scan2048(H2, C2, Wsum);
  int b2a = findbin(C2, r1a);
  uint32_t bel2a = b2a ? C2[b2a - 1] : 0u;
  uint32_t r2a = r1a - bel2a;

  int sameB1 = needB && (C1[b1a] > rb);
  int b2b = -1; uint32_t r2b = 0;
  if (sameB1) {
    uint32_t r1b = rb - bel1a;
    b2b = findbin(C2, r1b);
    uint32_t bel2b = b2b ? C2[b2b - 1] : 0u;
    r2b = r1b - bel2b;
  }

  histpass3(sl, ((uint32_t)b1a << 11) | (uint32_t)b2a, H2); scan2048(H2, C2, Wsum);
  int b3a = findbin(C2, r2a);
  *vA = key2f(((uint32_t)b1a << 21) | ((uint32_t)b2a << 10) | (uint32_t)b3a);

  int doneB = 0;
  if (needB && sameB1 && b2b == b2a) {
    int b3b = findbin(C2, r2b);
    *vB = key2f(((uint32_t)b1a << 21) | ((uint32_t)b2a << 10) | (uint32_t)b3b);
    doneB = 1;
  }
  if (needB && !doneB) {
    int b1b, b2bb; uint32_t r2bb;
    if (sameB1) { b1b = b1a; b2bb = b2b; r2bb = r2b; }
    else {
      b1b = findbin(C1, rb);
      uint32_t bel1b = b1b ? C1[b1b - 1] : 0u;
      uint32_t r1b = rb - bel1b;
      histpass2(sl, b1b, H2); scan2048(H2, C2, Wsum);
      b2bb = findbin(C2, r1b);
      uint32_t bel2 = b2bb ? C2[b2bb - 1] : 0u;
      r2bb = r1b - bel2;
    }
    histpass3(sl, ((uint32_t)b1b << 11) | (uint32_t)b2bb, H2); scan2048(H2, C2, Wsum);
    int b3b = findbin(C2, r2bb);
    *vB = key2f(((uint32_t)b1b << 21) | ((uint32_t)b2bb << 10) | (uint32_t)b3b);
  }
  if (!needB) *vB = *vA;
}

// block sum reduce of a double; result valid on thread 0
__device__ double blockReduceD(double v, double* tmp) {
  int lane = threadIdx.x & 63, wid = threadIdx.x >> 6;
  for (int d = 32; d > 0; d >>= 1) v += __shfl_down(v, d);
  if (lane == 0) tmp[wid] = v;
  __syncthreads();
  double r = 0.0;
  if (threadIdx.x < 16) r = tmp[threadIdx.x];
  for (int d = 8; d > 0; d >>= 1) r += __shfl_down(r, d);
  __syncthreads();
  return r;
}

__global__ __launch_bounds__(NTHREADS) void feat_kernel(const float* __restrict__ vol,
                                                        float* __restrict__ feats) {
  __shared__ uint32_t H1[2048];
  __shared__ uint32_t C1[2048];
  __shared__ uint32_t H2[2048];
  __shared__ uint32_t C2[2048];
  __shared__ uint32_t Wsum[16];
  __shared__ double   tmpD[16];
  __shared__ uint32_t hist16[16];
  __shared__ uint32_t smaxkey;

  const int tid = threadIdx.x;
  const int lane = tid & 63;
  const float* sl = vol + (size_t)blockIdx.x * NPIX;

  // ---- P1: level-1 histogram (key>>21) + global max ----
  H1[2 * tid] = 0; H1[2 * tid + 1] = 0;
  if (tid == 0) smaxkey = 0u;
  if (tid < 16) hist16[tid] = 0u;
  __syncthreads();
  uint32_t mk = 0u;
#pragma unroll 8
  for (int t = 0; t < EPT; ++t) {
    uint32_t k = f2key(sl[tid + t * NTHREADS]);
    mk = max(mk, k);
    atomicAdd(&H1[k >> 21], 1u);
  }
  for (int d = 32; d > 0; d >>= 1) { uint32_t o = __shfl_down(mk, d); mk = max(mk, o); }
  if (lane == 0) atomicMax(&smaxkey, mk);
  __syncthreads();
  scan2048(H1, C1, Wsum);

  // ---- threshold = order statistic at rank 52428 (fr==0 in f32) ----
  uint32_t cnt_lt;
  float thresh = select_rank_cnt(sl, THRESH_RANK, C1, H2, C2, Wsum, &cnt_lt);
  uint32_t n  = NPIX - cnt_lt;         // count of (v >= thresh)
  uint32_t t0 = cnt_lt;                // masked sorted idx j == overall rank t0+j
  float vmax = key2f(smaxkey);
  float vminf = thresh;                // smallest masked value is thresh itself

  // ---- P5: masked raw moments, |x|, centroid, 16-bin histogram ----
  float rng = vmax - vminf;
  float denomf = (rng > 0.0f) ? rng : 1.0f;
  double sx = 0, sx2 = 0, sx3 = 0, sx4 = 0, sab = 0;
  uint32_t syi = 0, sxi = 0;
#pragma unroll 4
  for (int t = 0; t < EPT; ++t) {
    int i = tid + t * NTHREADS;
    float v = sl[i];
    if (v >= thresh) {
      double dv = (double)v;
      double d2 = dv * dv;
      sx += dv; sx2 += d2; sx3 += d2 * dv; sx4 += d2 * d2;
      sab += fabs(dv);
      syi += (uint32_t)(i >> 8);
      sxi += (uint32_t)(i & 255);
      float bf = floorf((v - vminf) / denomf * 16.0f);
      int bin = (int)bf; bin = bin < 0 ? 0 : (bin > 15 ? 15 : bin);
      atomicAdd(&hist16[bin], 1u);
    }
  }
  sx  = blockReduceD(sx, tmpD);
  sx2 = blockReduceD(sx2, tmpD);
  sx3 = blockReduceD(sx3, tmpD);
  sx4 = blockReduceD(sx4, tmpD);
  sab = blockReduceD(sab, tmpD);
  double syid = blockReduceD((double)syi, tmpD);
  double sxid = blockReduceD((double)sxi, tmpD);

  // ---- masked quantiles (f32 position arithmetic, like the reference) ----
  float nm1f = (float)n - 1.0f;
  int last = (int)nm1f;
  const float ps[3] = {0.25f, 0.5f, 0.75f};
  float qv[3];
  for (int qi = 0; qi < 3; ++qi) {
    float pos = ps[qi] * nm1f;
    float lof = floorf(pos);
    float fr = pos - lof;
    int lo_i = (int)lof;
    int hi_i = min(lo_i + 1, last);
    int needB = (fr > 0.0f) && (hi_i != lo_i);
    float vlo, vhi;
    select_pair(sl, t0 + (uint32_t)lo_i, t0 + (uint32_t)hi_i, needB,
                C1, H2, C2, Wsum, &vlo, &vhi);
    qv[qi] = vlo * (1.0f - fr) + vhi * fr;
  }

  // ---- gradient magnitude pass (numpy gradient semantics) ----
  double sg = 0, sg2 = 0;
#pragma unroll 4
  for (int t = 0; t < EPT; ++t) {
    int i = tid + t * NTHREADS;
    float v = sl[i];
    if (v >= thresh) {
      int y = i >> 8, x = i & 255;
      float gy = (y == 0)   ? (sl[i + 256] - v)
               : (y == 255) ? (v - sl[i - 256])
                            : 0.5f * (sl[i + 256] - sl[i - 256]);
      float gx = (x == 0)   ? (sl[i + 1] - v)
               : (x == 255) ? (v - sl[i - 1])
                            : 0.5f * (sl[i + 1] - sl[i - 1]);
      float gm = sqrtf(gy * gy + gx * gx);
      sg += (double)gm;
      sg2 += (double)gm * (double)gm;
    }
  }
  sg  = blockReduceD(sg, tmpD);
  sg2 = blockReduceD(sg2, tmpD);

  // ---- finalize features (thread 0) ----
  if (tid == 0) {
    double dn = (double)n;
    double mean = sx / dn;
    double M2 = sx2 - sx * sx / dn;                         // sum c^2
    double std_ = sqrt(M2 / dn);
    double se = fmax(std_, 1e-6);
    double S3 = sx3 - 3.0 * mean * sx2 + 2.0 * dn * mean * mean * mean;
    double S4 = sx4 - 4.0 * mean * sx3 + 6.0 * mean * mean * sx2
                - 3.0 * dn * mean * mean * mean * mean;
    double skew = (S3 / dn) / (se * se * se);
    skew = fmin(fmax(skew, -50.0), 50.0);
    double kurt = (S4 / dn) / (se * se * se * se);
    kurt = fmin(fmax(kurt, 0.0), 100.0);
    double msq = sx2 / dn;
    double absmean = sab / dn;

    double ent = 0.0;
    double nden = fmax(dn, 1.0);
    for (int bi = 0; bi < 16; ++bi) {
      double p = fmax((double)hist16[bi] / nden, 1e-6);
      ent -= p * log(p);
    }
    if (fabsf(vminf - vmax) <= 1e-8f + 1e-5f * fabsf(vmax)) ent = 0.0;

    double gmean = sg / dn;
    double gstd = sqrt(fmax(sg2 / dn - gmean * gmean, 0.0));
    double cy = (syid / dn) / 255.0;
    double cx = (sxid / dn) / 255.0;
    double frac = dn / (double)NPIX;

    float* fo = feats + (size_t)blockIdx.x * NFEAT;
    fo[0]  = (float)mean;  fo[1]  = (float)std_;  fo[2]  = vminf;      fo[3]  = vmax;
    fo[4]  = qv[0];        fo[5]  = qv[1];        fo[6]  = qv[2];      fo[7]  = (float)msq;
    fo[8]  = (float)ent;   fo[9]  = (float)skew;  fo[10] = (float)kurt; fo[11] = (float)frac;
    fo[12] = (float)gmean; fo[13] = (float)gstd;  fo[14] = (float)cy;  fo[15] = (float)cx;
    fo[16] = (float)frac;  fo[17] = (float)absmean;
  }
}

__global__ __launch_bounds__(EMB) void token_kernel(const float* __restrict__ feats,
                                                    const float* __restrict__ W,
                                                    const float* __restrict__ b,
                                                    const float* __restrict__ gamma,
                                                    const float* __restrict__ beta,
                                                    float* __restrict__ out,
                                                    float* __restrict__ maskout) {
  __shared__ float f[NFEAT];
  __shared__ float red[4];
  int s = blockIdx.x, e = threadIdx.x;
  if (e < NFEAT) f[e] = feats[(size_t)s * NFEAT + e];
  __syncthreads();
  float acc = b[e];
#pragma unroll
  for (int k = 0; k < NFEAT; ++k) acc += f[k] * W[k * EMB + e];
  int lane = e & 63, wd = e >> 6;
  float sum = acc;
  for (int d = 32; d > 0; d >>= 1) sum += __shfl_down(sum, d);
  if (lane == 0) red[wd] = sum;
  __syncthreads();
  float mu = (red[0] + red[1] + red[2] + red[3]) * (1.0f / EMB);
  float c = acc - mu;
  float s2 = c * c;
  for (int d = 32; d > 0; d >>= 1) s2 += __shfl_down(s2, d);
  __syncthreads();
  if (lane == 0) red[wd] = s2;
  __syncthreads();
  float var = (red[0] + red[1] + red[2] + red[3]) * (1.0f / EMB);
  float o = c / sqrtf(var + 1e-5f) * gamma[e] + beta[e];
  out[(size_t)s * EMB + e] = o;
  if (e == 0) maskout[s] = 0.0f;
}

extern "C" void kernel_launch(void* const* d_in, const int* in_sizes, int n_in,
                              void* d_out, int out_size, void* d_ws, size_t ws_size,
                              hipStream_t stream) {
  const float* vol   = (const float*)d_in[0];
  const float* W     = (const float*)d_in[1];
  const float* b     = (const float*)d_in[2];
  const float* gamma = (const float*)d_in[3];
  const float* beta  = (const float*)d_in[4];
  float* out = (float*)d_out;
  float* feats = (float*)d_ws;

  feat_kernel<<<NSLICES, NTHREADS, 0, stream>>>(vol, feats);
  token_kernel<<<NSLICES, EMB, 0, stream>>>(feats, W, b, gamma, beta,
                                            out, out + (size_t)NSLICES * EMB);
}

// Round 2
// 419.010 us; speedup vs baseline: 1.7353x; 1.7353x over previous
//
#include <hip/hip_runtime.h>
#include <stdint.h>

#define NPIX     65536
#define NTHREADS 1024
#define NSLICES  512
#define NFEAT    18
#define EMB      256
#define THRESH_RANK 52428u  // 0.8f*(65536-1) == 52428.0 exactly in f32 => fr == 0
#define GCAP     12288      // gathered-key LDS capacity (48 KB)
#define MAXBINS  10
#define EPT4     16         // float4 iterations per thread (16*4*1024 = 65536)

// ---------- sortable key mapping (monotonic with float order) ----------
__device__ __forceinline__ uint32_t f2key(float f) {
  uint32_t u = __float_as_uint(f);
  return u ^ ((u & 0x80000000u) ? 0xFFFFFFFFu : 0x80000000u);
}
__device__ __forceinline__ float key2f(uint32_t k) {
  uint32_t u = (k & 0x80000000u) ? (k ^ 0x80000000u) : ~k;
  return __uint_as_float(u);
}

// smallest index b in [0,2048) with C[b] > r  (C = inclusive prefix)
__device__ __forceinline__ int findbin(const uint32_t* C, uint32_t r) {
  int lo = 0, hi = 2047;
  while (lo < hi) { int mid = (lo + hi) >> 1; if (C[mid] > r) hi = mid; else lo = mid + 1; }
  return lo;
}

// in-place inclusive prefix sum over 2048 bins (1024 threads, 2 bins/thread)
__device__ void scan2048(uint32_t* H, uint32_t* Wsum) {
  int tid = threadIdx.x, lane = tid & 63, wid = tid >> 6;
  uint32_t a1 = H[2 * tid + 1];
  uint32_t v = H[2 * tid] + a1;
  for (int d = 1; d < 64; d <<= 1) {
    uint32_t t = __shfl_up(v, d);
    if (lane >= d) v += t;
  }
  if (lane == 63) Wsum[wid] = v;
  __syncthreads();
  uint32_t woff = 0;
  for (int w = 0; w < wid; ++w) woff += Wsum[w];
  v += woff;
  H[2 * tid + 1] = v;
  H[2 * tid]     = v - a1;
  __syncthreads();
}

// ---- global fallback histogram passes (rare; correctness safety net) ----
__device__ void histpass2(const float* sl, int b1, uint32_t* H) {
  int tid = threadIdx.x;
  __syncthreads();
  H[2 * tid] = 0; H[2 * tid + 1] = 0;
  __syncthreads();
  for (int t = 0; t < 64; ++t) {
    uint32_t k = f2key(sl[tid + t * NTHREADS]);
    if ((int)(k >> 21) == b1) atomicAdd(&H[(k >> 10) & 2047u], 1u);
  }
  __syncthreads();
}
__device__ void histpass3(const float* sl, uint32_t pfx, uint32_t* H) {
  int tid = threadIdx.x;
  __syncthreads();
  H[2 * tid] = 0; H[2 * tid + 1] = 0;
  __syncthreads();
  for (int t = 0; t < 64; ++t) {
    uint32_t k = f2key(sl[tid + t * NTHREADS]);
    if ((k >> 10) == pfx) atomicAdd(&H[k & 1023u], 1u);
  }
  __syncthreads();
}

__device__ uint32_t global_select_key(const float* sl, uint32_t rank, const uint32_t* C1,
                                      uint32_t* H2, uint32_t* Wsum, uint32_t* bel_out) {
  int b1 = findbin(C1, rank);
  uint32_t bel1 = b1 ? C1[b1 - 1] : 0u;
  uint32_t r1 = rank - bel1;
  histpass2(sl, b1, H2); scan2048(H2, Wsum);
  int b2 = findbin(H2, r1);
  uint32_t bel2 = b2 ? H2[b2 - 1] : 0u;
  uint32_t r2 = r1 - bel2;
  histpass3(sl, ((uint32_t)b1 << 11) | (uint32_t)b2, H2); scan2048(H2, Wsum);
  int b3 = findbin(H2, r2);
  uint32_t bel3 = b3 ? H2[b3 - 1] : 0u;
  *bel_out = bel1 + bel2 + bel3;
  return ((uint32_t)b1 << 21) | ((uint32_t)b2 << 10) | (uint32_t)b3;
}

// ---- in-LDS select on a gathered bin segment; returns key; bel = count below within bin ----
__device__ uint32_t lds_select(const uint32_t* G, uint32_t base, uint32_t c, uint32_t bin,
                               uint32_t r_in, uint32_t* H, uint32_t* Wsum, uint32_t* bel_out) {
  int tid = threadIdx.x;
  __syncthreads();                     // protect H from previous readers
  H[2 * tid] = 0; H[2 * tid + 1] = 0;
  __syncthreads();
  for (uint32_t i = tid; i < c; i += NTHREADS) atomicAdd(&H[(G[base + i] >> 10) & 2047u], 1u);
  __syncthreads();
  scan2048(H, Wsum);
  int b2 = findbin(H, r_in);
  uint32_t bel2 = b2 ? H[b2 - 1] : 0u;
  uint32_t r2 = r_in - bel2;
  uint32_t pfx = (bin << 11) | (uint32_t)b2;
  __syncthreads();
  H[2 * tid] = 0; H[2 * tid + 1] = 0;
  __syncthreads();
  for (uint32_t i = tid; i < c; i += NTHREADS) {
    uint32_t k = G[base + i];
    if ((k >> 10) == pfx) atomicAdd(&H[k & 1023u], 1u);
  }
  __syncthreads();
  scan2048(H, Wsum);
  int b3 = findbin(H, r2);
  uint32_t bel3 = b3 ? H[b3 - 1] : 0u;
  *bel_out = bel2 + bel3;
  return (bin << 21) | ((uint32_t)b2 << 10) | (uint32_t)b3;
}

// resolve the value of overall rank `rank`: LDS path if its bin was gathered, else global
__device__ float rank_value(const float* sl, uint32_t rank, const uint32_t* C1,
                            const uint32_t* G, int nreg, const uint32_t* rbin,
                            const uint32_t* roff, const uint32_t* rcnt,
                            uint32_t* H2, uint32_t* Wsum) {
  int b = findbin(C1, rank);
  uint32_t below = b ? C1[b - 1] : 0u;
  int j = -1;
  for (int i = 0; i < nreg; ++i) if (rbin[i] == (uint32_t)b) { j = i; break; }
  uint32_t bel, key;
  if (j >= 0) key = lds_select(G, roff[j], rcnt[j], (uint32_t)b, rank - below, H2, Wsum, &bel);
  else        key = global_select_key(sl, rank, C1, H2, Wsum, &bel);
  return key2f(key);
}

// block sum reduce of a double; result valid on all threads of wave 0, esp. thread 0
__device__ double blockReduceD(double v, double* tmp) {
  int lane = threadIdx.x & 63, wid = threadIdx.x >> 6;
  for (int d = 32; d > 0; d >>= 1) v += __shfl_down(v, d);
  if (lane == 0) tmp[wid] = v;
  __syncthreads();
  double r = 0.0;
  if (threadIdx.x < 16) r = tmp[threadIdx.x];
  for (int d = 8; d > 0; d >>= 1) r += __shfl_down(r, d);
  __syncthreads();
  return r;
}

__global__ __launch_bounds__(NTHREADS) void feat_kernel(const float* __restrict__ vol,
                                                        float* __restrict__ feats) {
  __shared__ uint32_t HC1[2048];        // level-1 histogram -> inclusive prefix (C1)
  __shared__ uint32_t HC2[2048];        // scratch histogram for selects
  __shared__ uint32_t G[GCAP];          // gathered keys
  __shared__ uint32_t Wsum[16];
  __shared__ double   tmpD[16];
  __shared__ uint32_t hist16[16];
  __shared__ uint32_t smaxkey;
  __shared__ int      s_nreg, s_b1t, s_r0ok;
  __shared__ uint32_t s_cntlo;
  __shared__ uint32_t s_rbin[MAXBINS], s_roff[MAXBINS], s_rcnt[MAXBINS], s_gctr[MAXBINS];

  const int tid  = threadIdx.x;
  const int lane = tid & 63;
  const float*  sl  = vol + (size_t)blockIdx.x * NPIX;
  const float4* sl4 = (const float4*)sl;

  // ---- Pass A: level-1 histogram (key>>21) + global max ----
  HC1[2 * tid] = 0; HC1[2 * tid + 1] = 0;
  if (tid == 0) smaxkey = 0u;
  if (tid < 16) hist16[tid] = 0u;
  __syncthreads();
  uint32_t mk = 0u;
#pragma unroll 4
  for (int t = 0; t < EPT4; ++t) {
    float4 f = sl4[tid + t * NTHREADS];
    uint32_t k0 = f2key(f.x), k1 = f2key(f.y), k2 = f2key(f.z), k3 = f2key(f.w);
    mk = max(mk, max(max(k0, k1), max(k2, k3)));
    atomicAdd(&HC1[k0 >> 21], 1u);
    atomicAdd(&HC1[k1 >> 21], 1u);
    atomicAdd(&HC1[k2 >> 21], 1u);
    atomicAdd(&HC1[k3 >> 21], 1u);
  }
  for (int d = 32; d > 0; d >>= 1) { uint32_t o = __shfl_down(mk, d); mk = max(mk, o); }
  if (lane == 0) atomicMax(&smaxkey, mk);
  __syncthreads();
  scan2048(HC1, Wsum);   // HC1 is now C1 (inclusive prefix)

  // ---- region planning (thread 0): threshold bin + candidate quantile bins ----
  if (tid == 0) {
    int b1t = findbin(HC1, THRESH_RANK);
    uint32_t clo  = b1t ? HC1[b1t - 1] : 0u;      // min possible cnt_lt
    uint32_t cmax = min(THRESH_RANK, HC1[b1t] - 1u); // max possible cnt_lt
    s_b1t = b1t; s_cntlo = clo;
    int nreg = 0; uint32_t total = 0;
    auto tryadd = [&](int b) {
      for (int j = 0; j < nreg; ++j) if (s_rbin[j] == (uint32_t)b) return;
      uint32_t c = HC1[b] - (b ? HC1[b - 1] : 0u);
      if (nreg < MAXBINS && total + c <= GCAP) {
        s_rbin[nreg] = (uint32_t)b; s_rcnt[nreg] = c; s_roff[nreg] = total; s_gctr[nreg] = 0u;
        total += c; ++nreg;
      }
    };
    tryadd(b1t);
    s_r0ok = (nreg > 0 && s_rbin[0] == (uint32_t)b1t) ? 1 : 0;
    const float pp[3] = {0.25f, 0.5f, 0.75f};
    for (int qi = 0; qi < 3; ++qi) {
      float p = pp[qi];
      uint32_t rlo = clo  + (uint32_t)(int)floorf(p * ((float)(NPIX - clo)  - 1.0f));
      uint32_t rhi = cmax + (uint32_t)(int)floorf(p * ((float)(NPIX - cmax) - 1.0f)) + 1u;
      if (rhi > NPIX - 1u) rhi = NPIX - 1u;
      if (rlo > rhi) rlo = rhi;
      int ba = findbin(HC1, rlo), bb = findbin(HC1, rhi);
      if (bb > ba + 8) bb = ba + 8;   // bound thread-0 serial work; misses -> fallback
      for (int b = ba; b <= bb; ++b) tryadd(b);
    }
    s_nreg = nreg;
  }
  __syncthreads();
  const int nreg = s_nreg;

  // ---- Gather pass: collect keys of all candidate bins into LDS ----
#pragma unroll 4
  for (int t = 0; t < EPT4; ++t) {
    float4 f = sl4[tid + t * NTHREADS];
    uint32_t k0 = f2key(f.x), k1 = f2key(f.y), k2 = f2key(f.z), k3 = f2key(f.w);
#define TRYGATHER(kk)                                                        \
    {                                                                        \
      uint32_t b = (kk) >> 21;                                               \
      for (int j = 0; j < nreg; ++j) {                                       \
        if (s_rbin[j] == b) {                                                \
          uint32_t pos = s_roff[j] + atomicAdd(&s_gctr[j], 1u);              \
          G[pos] = (kk); break;                                              \
        }                                                                    \
      }                                                                      \
    }
    TRYGATHER(k0) TRYGATHER(k1) TRYGATHER(k2) TRYGATHER(k3)
#undef TRYGATHER
  }
  __syncthreads();

  // ---- threshold = order statistic at rank 52428 ----
  uint32_t bel, key;
  if (s_r0ok) {
    key = lds_select(G, s_roff[0], s_rcnt[0], (uint32_t)s_b1t,
                     THRESH_RANK - s_cntlo, HC2, Wsum, &bel);
    bel += s_cntlo;
  } else {
    key = global_select_key(sl, THRESH_RANK, HC1, HC2, Wsum, &bel);
  }
  const uint32_t cnt_lt = bel;
  const float thresh = key2f(key);
  const uint32_t n  = NPIX - cnt_lt;
  const uint32_t t0 = cnt_lt;
  const float vmax  = key2f(smaxkey);
  const float vminf = thresh;

  // ---- masked quantiles (f32 position arithmetic, matching the reference) ----
  float nm1f = (float)n - 1.0f;
  int last = (int)nm1f;
  float qv[3];
  const float ps[3] = {0.25f, 0.5f, 0.75f};
#pragma unroll
  for (int qi = 0; qi < 3; ++qi) {
    float pos = ps[qi] * nm1f;
    float lof = floorf(pos);
    float fr = pos - lof;
    int lo_i = (int)lof;
    int hi_i = min(lo_i + 1, last);
    float va = rank_value(sl, t0 + (uint32_t)lo_i, HC1, G, nreg, s_rbin, s_roff, s_rcnt, HC2, Wsum);
    float vb = va;
    if (fr > 0.0f && hi_i != lo_i)
      vb = rank_value(sl, t0 + (uint32_t)hi_i, HC1, G, nreg, s_rbin, s_roff, s_rcnt, HC2, Wsum);
    qv[qi] = va * (1.0f - fr) + vb * fr;
  }

  // ---- Pass D (fused): masked moments, |x|, centroid, hist16, gradient ----
  float rng = vmax - vminf;
  float denomf = (rng > 0.0f) ? rng : 1.0f;
  float sxl = 0, sx2l = 0, sx3l = 0, sx4l = 0, sabl = 0, sgl = 0, sg2l = 0;
  uint32_t syi = 0, sxi = 0;
#pragma unroll 4
  for (int t = 0; t < EPT4; ++t) {
    int i4 = tid + t * NTHREADS;
    float4 v = sl4[i4];
    bool m0 = v.x >= thresh, m1 = v.y >= thresh, m2 = v.z >= thresh, m3 = v.w >= thresh;
    if (m0 | m1 | m2 | m3) {
      int y = i4 >> 6, xb = (i4 & 63) << 2;
      float4 up = sl4[(y > 0)   ? (i4 - 64) : i4];
      float4 dn = sl4[(y < 255) ? (i4 + 64) : i4];
      float lf = (xb > 0)   ? sl[4 * i4 - 1] : 0.0f;
      float rt = (xb < 252) ? sl[4 * i4 + 4] : 0.0f;
#define DOC(mc, vc, upc, dnc, lv, rv, xc)                                      \
      if (mc) {                                                                \
        float gy = (y == 0) ? (dnc - vc) : ((y == 255) ? (vc - upc) : 0.5f * (dnc - upc)); \
        int xx = xb + (xc);                                                    \
        float gx = (xx == 0) ? (rv - vc) : ((xx == 255) ? (vc - lv) : 0.5f * (rv - lv));   \
        float gm = sqrtf(gy * gy + gx * gx);                                   \
        sgl += gm; sg2l += gm * gm;                                            \
        float v2 = vc * vc;                                                    \
        sxl += vc; sx2l += v2; sx3l += v2 * vc; sx4l += v2 * v2;               \
        sabl += fabsf(vc);                                                     \
        syi += (uint32_t)y; sxi += (uint32_t)xx;                               \
        float bf = floorf((vc - vminf) / denomf * 16.0f);                      \
        int bin = (int)bf; bin = bin < 0 ? 0 : (bin > 15 ? 15 : bin);          \
        atomicAdd(&hist16[bin], 1u);                                           \
      }
      DOC(m0, v.x, up.x, dn.x, lf,  v.y, 0)
      DOC(m1, v.y, up.y, dn.y, v.x, v.z, 1)
      DOC(m2, v.z, up.z, dn.z, v.y, v.w, 2)
      DOC(m3, v.w, up.w, dn.w, v.z, rt,  3)
#undef DOC
    }
  }
  double sx  = blockReduceD((double)sxl,  tmpD);
  double sx2 = blockReduceD((double)sx2l, tmpD);
  double sx3 = blockReduceD((double)sx3l, tmpD);
  double sx4 = blockReduceD((double)sx4l, tmpD);
  double sab = blockReduceD((double)sabl, tmpD);
  double sg  = blockReduceD((double)sgl,  tmpD);
  double sg2 = blockReduceD((double)sg2l, tmpD);
  double syid = blockReduceD((double)syi, tmpD);
  double sxid = blockReduceD((double)sxi, tmpD);

  // ---- finalize features (thread 0) ----
  if (tid == 0) {
    double dn = (double)n;
    double mean = sx / dn;
    double M2 = sx2 - sx * sx / dn;
    double std_ = sqrt(M2 / dn);
    double se = fmax(std_, 1e-6);
    double S3 = sx3 - 3.0 * mean * sx2 + 2.0 * dn * mean * mean * mean;
    double S4 = sx4 - 4.0 * mean * sx3 + 6.0 * mean * mean * sx2
                - 3.0 * dn * mean * mean * mean * mean;
    double skew = (S3 / dn) / (se * se * se);
    skew = fmin(fmax(skew, -50.0), 50.0);
    double kurt = (S4 / dn) / (se * se * se * se);
    kurt = fmin(fmax(kurt, 0.0), 100.0);
    double msq = sx2 / dn;
    double absmean = sab / dn;

    double ent = 0.0;
    double nden = fmax(dn, 1.0);
    for (int bi = 0; bi < 16; ++bi) {
      double p = fmax((double)hist16[bi] / nden, 1e-6);
      ent -= p * log(p);
    }
    if (fabsf(vminf - vmax) <= 1e-8f + 1e-5f * fabsf(vmax)) ent = 0.0;

    double gmean = sg / dn;
    double gstd = sqrt(fmax(sg2 / dn - gmean * gmean, 0.0));
    double cy = (syid / dn) / 255.0;
    double cx = (sxid / dn) / 255.0;
    double frac = dn / (double)NPIX;

    float* fo = feats + (size_t)blockIdx.x * NFEAT;
    fo[0]  = (float)mean;  fo[1]  = (float)std_;  fo[2]  = vminf;       fo[3]  = vmax;
    fo[4]  = qv[0];        fo[5]  = qv[1];        fo[6]  = qv[2];       fo[7]  = (float)msq;
    fo[8]  = (float)ent;   fo[9]  = (float)skew;  fo[10] = (float)kurt; fo[11] = (float)frac;
    fo[12] = (float)gmean; fo[13] = (float)gstd;  fo[14] = (float)cy;   fo[15] = (float)cx;
    fo[16] = (float)frac;  fo[17] = (float)absmean;
  }
}

__global__ __launch_bounds__(EMB) void token_kernel(const float* __restrict__ feats,
                                                    const float* __restrict__ W,
                                                    const float* __restrict__ b,
                                                    const float* __restrict__ gamma,
                                                    const float* __restrict__ beta,
                                                    float* __restrict__ out,
                                                    float* __restrict__ maskout) {
  __shared__ float f[NFEAT];
  __shared__ float red[4];
  int s = blockIdx.x, e = threadIdx.x;
  if (e < NFEAT) f[e] = feats[(size_t)s * NFEAT + e];
  __syncthreads();
  float acc = b[e];
#pragma unroll
  for (int k = 0; k < NFEAT; ++k) acc += f[k] * W[k * EMB + e];
  int lane = e & 63, wd = e >> 6;
  float sum = acc;
  for (int d = 32; d > 0; d >>= 1) sum += __shfl_down(sum, d);
  if (lane == 0) red[wd] = sum;
  __syncthreads();
  float mu = (red[0] + red[1] + red[2] + red[3]) * (1.0f / EMB);
  float c = acc - mu;
  float s2 = c * c;
  for (int d = 32; d > 0; d >>= 1) s2 += __shfl_down(s2, d);
  __syncthreads();
  if (lane == 0) red[wd] = s2;
  __syncthreads();
  float var = (red[0] + red[1] + red[2] + red[3]) * (1.0f / EMB);
  float o = c / sqrtf(var + 1e-5f) * gamma[e] + beta[e];
  out[(size_t)s * EMB + e] = o;
  if (e == 0) maskout[s] = 0.0f;
}

extern "C" void kernel_launch(void* const* d_in, const int* in_sizes, int n_in,
                              void* d_out, int out_size, void* d_ws, size_t ws_size,
                              hipStream_t stream) {
  const float* vol   = (const float*)d_in[0];
  const float* W     = (const float*)d_in[1];
  const float* b     = (const float*)d_in[2];
  const float* gamma = (const float*)d_in[3];
  const float* beta  = (const float*)d_in[4];
  float* out = (float*)d_out;
  float* feats = (float*)d_ws;

  feat_kernel<<<NSLICES, NTHREADS, 0, stream>>>(vol, feats);
  token_kernel<<<NSLICES, EMB, 0, stream>>>(feats, W, b, gamma, beta,
                                            out, out + (size_t)NSLICES * EMB);
}

// Round 3
// 191.682 us; speedup vs baseline: 3.7933x; 2.1860x over previous
//
#include <hip/hip_runtime.h>
#include <stdint.h>

#define NPIX     65536
#define NTHREADS 1024
#define NSLICES  512
#define NFEAT    18
#define EMB      256
#define THRESH_RANK 52428u  // 0.8f*(65536-1) == 52428.0 exactly in f32 => fr == 0
#define GCAP     12800      // gathered-key LDS capacity (50 KB)
#define MAXBINS  20
#define EPT4     16         // float4 iterations per thread

// ---------- sortable key mapping (monotonic with float order) ----------
__device__ __forceinline__ uint32_t f2key(float f) {
  uint32_t u = __float_as_uint(f);
  return u ^ ((u & 0x80000000u) ? 0xFFFFFFFFu : 0x80000000u);
}
__device__ __forceinline__ float key2f(uint32_t k) {
  uint32_t u = (k & 0x80000000u) ? (k ^ 0x80000000u) : ~k;
  return __uint_as_float(u);
}

// ---------------- block-wide helpers (Pass A scan + rare fallback) -------------
__device__ __forceinline__ int findbin(const uint32_t* C, uint32_t r) {
  int lo = 0, hi = 2047;
  while (lo < hi) { int mid = (lo + hi) >> 1; if (C[mid] > r) hi = mid; else lo = mid + 1; }
  return lo;
}

__device__ void scan2048(uint32_t* H, uint32_t* Wsum) {
  int tid = threadIdx.x, lane = tid & 63, wid = tid >> 6;
  uint32_t a1 = H[2 * tid + 1];
  uint32_t v = H[2 * tid] + a1;
  for (int d = 1; d < 64; d <<= 1) {
    uint32_t t = __shfl_up(v, d);
    if (lane >= d) v += t;
  }
  if (lane == 63) Wsum[wid] = v;
  __syncthreads();
  uint32_t woff = 0;
  for (int w = 0; w < wid; ++w) woff += Wsum[w];
  v += woff;
  H[2 * tid + 1] = v;
  H[2 * tid]     = v - a1;
  __syncthreads();
}

__device__ void histpass2(const float* sl, int b1, uint32_t* H) {
  int tid = threadIdx.x;
  __syncthreads();
  H[2 * tid] = 0; H[2 * tid + 1] = 0;
  __syncthreads();
  for (int t = 0; t < 64; ++t) {
    uint32_t k = f2key(sl[tid + t * NTHREADS]);
    if ((int)(k >> 21) == b1) atomicAdd(&H[(k >> 10) & 2047u], 1u);
  }
  __syncthreads();
}
__device__ void histpass3(const float* sl, uint32_t pfx, uint32_t* H) {
  int tid = threadIdx.x;
  __syncthreads();
  H[2 * tid] = 0; H[2 * tid + 1] = 0;
  __syncthreads();
  for (int t = 0; t < 64; ++t) {
    uint32_t k = f2key(sl[tid + t * NTHREADS]);
    if ((k >> 10) == pfx) atomicAdd(&H[k & 1023u], 1u);
  }
  __syncthreads();
}

__device__ uint32_t global_select_key(const float* sl, uint32_t rank, const uint32_t* C1,
                                      uint32_t* H2, uint32_t* Wsum, uint32_t* bel_out) {
  int b1 = findbin(C1, rank);
  uint32_t bel1 = b1 ? C1[b1 - 1] : 0u;
  uint32_t r1 = rank - bel1;
  histpass2(sl, b1, H2); scan2048(H2, Wsum);
  int b2 = findbin(H2, r1);
  uint32_t bel2 = b2 ? H2[b2 - 1] : 0u;
  uint32_t r2 = r1 - bel2;
  histpass3(sl, ((uint32_t)b1 << 11) | (uint32_t)b2, H2); scan2048(H2, Wsum);
  int b3 = findbin(H2, r2);
  uint32_t bel3 = b3 ? H2[b3 - 1] : 0u;
  *bel_out = bel1 + bel2 + bel3;
  return ((uint32_t)b1 << 21) | ((uint32_t)b2 << 10) | (uint32_t)b3;
}

// ---------------- wave-synchronous (wave 0 only) helpers ----------------------
__device__ __forceinline__ int wfind2048(const uint32_t* C, uint32_t r, int lane) {
  unsigned long long m = __ballot(C[lane * 32 + 31] > r);
  int chunk = __builtin_ctzll(m);
  unsigned long long m2 = __ballot((lane < 32) && (C[chunk * 32 + lane] > r));
  int off = __builtin_ctzll(m2);
  return chunk * 32 + off;
}
__device__ __forceinline__ int wfind1024(const uint32_t* C, uint32_t r, int lane) {
  unsigned long long m = __ballot(C[lane * 16 + 15] > r);
  int chunk = __builtin_ctzll(m);
  unsigned long long m2 = __ballot((lane < 16) && (C[chunk * 16 + lane] > r));
  int off = __builtin_ctzll(m2);
  return chunk * 16 + off;
}
__device__ void wscan2048(uint32_t* H, int lane) {
  uint32_t run = 0;
#pragma unroll
  for (int t = 0; t < 32; ++t) run += H[lane * 32 + t];
  uint32_t inc = run;
  for (int d = 1; d < 64; d <<= 1) { uint32_t o = __shfl_up(inc, d); if (lane >= d) inc += o; }
  uint32_t acc = inc - run;
#pragma unroll
  for (int t = 0; t < 32; ++t) { acc += H[lane * 32 + t]; H[lane * 32 + t] = acc; }
}
__device__ void wscan1024(uint32_t* H, int lane) {
  uint32_t run = 0;
#pragma unroll
  for (int t = 0; t < 16; ++t) run += H[lane * 16 + t];
  uint32_t inc = run;
  for (int d = 1; d < 64; d <<= 1) { uint32_t o = __shfl_up(inc, d); if (lane >= d) inc += o; }
  uint32_t acc = inc - run;
#pragma unroll
  for (int t = 0; t < 16; ++t) { acc += H[lane * 16 + t]; H[lane * 16 + t] = acc; }
}

struct SelState { int curBin; int curB2; };

// wave-0-uniform rank -> value; ok=false if bin not gathered (caller falls back)
__device__ float wave_rank_value(uint32_t rank, const uint32_t* C1, const uint32_t* G,
                                 const uint8_t* LUT, const uint32_t* roff, const uint32_t* rcnt,
                                 uint32_t* H2, uint32_t* H3, int lane, SelState* st,
                                 bool* ok, uint32_t* bel_out) {
  int b = wfind2048(C1, rank, lane);
  uint32_t below = b ? C1[b - 1] : 0u;
  int rj = LUT[b];
  if (rj == 0xFF) { *ok = false; return 0.0f; }
  uint32_t base = roff[rj], c = rcnt[rj];
  uint32_t r_in = rank - below;
  if (b != st->curBin) {
#pragma unroll
    for (int t = 0; t < 32; ++t) H2[lane * 32 + t] = 0;
    for (uint32_t i = lane; i < c; i += 64) atomicAdd(&H2[(G[base + i] >> 10) & 2047u], 1u);
    wscan2048(H2, lane);
    st->curBin = b; st->curB2 = -1;
  }
  int b2 = wfind2048(H2, r_in, lane);
  uint32_t bel2 = b2 ? H2[b2 - 1] : 0u;
  uint32_t r2 = r_in - bel2;
  uint32_t pfx = ((uint32_t)b << 11) | (uint32_t)b2;
  if (b2 != st->curB2) {
#pragma unroll
    for (int t = 0; t < 16; ++t) H3[lane * 16 + t] = 0;
    for (uint32_t i = lane; i < c; i += 64) {
      uint32_t k = G[base + i];
      if ((k >> 10) == pfx) atomicAdd(&H3[k & 1023u], 1u);
    }
    wscan1024(H3, lane);
    st->curB2 = b2;
  }
  int b3 = wfind1024(H3, r2, lane);
  *bel_out = below + bel2 + (b3 ? H3[b3 - 1] : 0u);
  *ok = true;
  return key2f(((uint32_t)b << 21) | ((uint32_t)b2 << 10) | (uint32_t)b3);
}

__global__ __launch_bounds__(NTHREADS) void feat_kernel(const float* __restrict__ vol,
                                                        float* __restrict__ feats) {
  __shared__ uint32_t HC1[2048];     // level-1 hist -> inclusive prefix C1
  __shared__ uint32_t HC2[2048];     // level-2 scratch (wave + block fallback)
  __shared__ uint32_t HL3[1024];     // level-3 scratch (wave path)
  __shared__ uint32_t G[GCAP];       // gathered keys
  __shared__ uint8_t  LUT[2048];     // bin -> region id (0xFF = none)
  __shared__ uint32_t Wsum[16];
  __shared__ double   tmpD9[16 * 9];
  __shared__ double   s_red[9];
  __shared__ uint32_t hist16[16];
  __shared__ uint32_t smaxkey;
  __shared__ uint32_t s_roff[MAXBINS], s_rcnt[MAXBINS], s_gctr[MAXBINS];
  __shared__ float    s_qA[3], s_qB[3], s_qfr[3];
  __shared__ int      s_qdup[3];
  __shared__ uint32_t s_qfb[6];
  __shared__ float    s_thresh;
  __shared__ uint32_t s_cnlt;
  __shared__ int      s_thr_ok;

  const int tid  = threadIdx.x;
  const int lane = tid & 63;
  const int wid  = tid >> 6;
  const float*  sl  = vol + (size_t)blockIdx.x * NPIX;
  const float4* sl4 = (const float4*)sl;

  // ---- Pass A: level-1 histogram (key>>21) + global max ----
  HC1[2 * tid] = 0; HC1[2 * tid + 1] = 0;
  if (tid == 0) smaxkey = 0u;
  if (tid < 16) hist16[tid] = 0u;
  __syncthreads();
  uint32_t mk = 0u;
#pragma unroll 4
  for (int t = 0; t < EPT4; ++t) {
    float4 f = sl4[tid + t * NTHREADS];
    uint32_t k0 = f2key(f.x), k1 = f2key(f.y), k2 = f2key(f.z), k3 = f2key(f.w);
    mk = max(mk, max(max(k0, k1), max(k2, k3)));
    atomicAdd(&HC1[k0 >> 21], 1u);
    atomicAdd(&HC1[k1 >> 21], 1u);
    atomicAdd(&HC1[k2 >> 21], 1u);
    atomicAdd(&HC1[k3 >> 21], 1u);
  }
  for (int d = 32; d > 0; d >>= 1) { uint32_t o = __shfl_down(mk, d); mk = max(mk, o); }
  if (lane == 0) atomicMax(&smaxkey, mk);
  __syncthreads();
  scan2048(HC1, Wsum);   // HC1 is now C1

  // ---- planning on wave 0 (uniform; lane 0 writes) ----
  if (tid < 64) {
#pragma unroll
    for (int t = 0; t < 32; ++t) LUT[lane * 32 + t] = 0xFF;
    int b1t = wfind2048(HC1, THRESH_RANK, lane);
    uint32_t clo  = b1t ? HC1[b1t - 1] : 0u;
    uint32_t cmax = min(THRESH_RANK, HC1[b1t] - 1u);
    int nreg = 0; uint32_t total = 0;
#define TRYADD(bb_)                                                            \
    { int _b = (bb_);                                                          \
      if (LUT[_b] == 0xFF) {                                                   \
        uint32_t _c = HC1[_b] - (_b ? HC1[_b - 1] : 0u);                       \
        if (nreg < MAXBINS && total + _c <= GCAP) {                            \
          if (lane == 0) { LUT[_b] = (uint8_t)nreg;                            \
            s_roff[nreg] = total; s_rcnt[nreg] = _c; s_gctr[nreg] = 0u; }      \
          total += _c; ++nreg; } } }
    TRYADD(b1t);
    int ba[3], bb[3];
    const float pp[3] = {0.25f, 0.5f, 0.75f};
#pragma unroll
    for (int qi = 0; qi < 3; ++qi) {
      float p = pp[qi];
      uint32_t rlo = clo  + (uint32_t)(int)floorf(p * ((float)(NPIX - clo)  - 1.0f));
      uint32_t rhi = cmax + (uint32_t)(int)floorf(p * ((float)(NPIX - cmax) - 1.0f)) + 1u;
      if (rhi > NPIX - 1u) rhi = NPIX - 1u;
      if (rlo > rhi) rlo = rhi;
      ba[qi] = wfind2048(HC1, rlo, lane);
      bb[qi] = wfind2048(HC1, rhi, lane);
      if (bb[qi] > ba[qi] + 8) bb[qi] = ba[qi] + 8;
    }
    for (int k = 0; k <= 8; ++k)
      for (int qi = 0; qi < 3; ++qi)
        if (ba[qi] + k <= bb[qi]) TRYADD(ba[qi] + k);
#undef TRYADD
    if (lane == 0) s_thr_ok = (LUT[b1t] != 0xFF) ? 1 : 0;
  }
  __syncthreads();

  // ---- gather pass (all threads): LUT lookup per element ----
#pragma unroll 4
  for (int t = 0; t < EPT4; ++t) {
    float4 f = sl4[tid + t * NTHREADS];
    uint32_t k0 = f2key(f.x), k1 = f2key(f.y), k2 = f2key(f.z), k3 = f2key(f.w);
#define TRYGATHER(kk)                                                          \
    { int rj = LUT[(kk) >> 21];                                                \
      if (rj != 0xFF) {                                                        \
        uint32_t pos = s_roff[rj] + atomicAdd(&s_gctr[rj], 1u);                \
        G[pos] = (kk);                                                         \
      } }
    TRYGATHER(k0) TRYGATHER(k1) TRYGATHER(k2) TRYGATHER(k3)
#undef TRYGATHER
  }
  __syncthreads();

  // ---- threshold (block fallback only if its bin wasn't gathered) ----
  if (!s_thr_ok) {
    uint32_t bel;
    uint32_t key = global_select_key(sl, THRESH_RANK, HC1, HC2, Wsum, &bel);
    if (tid == 0) { s_thresh = key2f(key); s_cnlt = bel; }
    __syncthreads();
  }

  // ---- wave-0 select phase: thresh (fast path) + quantiles, no barriers ----
  if (tid < 64) {
    SelState st; st.curBin = -1; st.curB2 = -1;
    uint32_t cnlt;
    if (s_thr_ok) {
      bool ok; uint32_t bel;
      float th = wave_rank_value(THRESH_RANK, HC1, G, LUT, s_roff, s_rcnt,
                                 HC2, HL3, lane, &st, &ok, &bel);
      cnlt = bel;
      if (lane == 0) { s_thresh = th; s_cnlt = bel; }
    } else {
      cnlt = s_cnlt;
    }
    uint32_t n  = NPIX - cnlt;
    uint32_t t0 = cnlt;
    float nm1f = (float)n - 1.0f;
    int last = (int)nm1f;
    const float pp[3] = {0.25f, 0.5f, 0.75f};
    for (int qi = 0; qi < 3; ++qi) {
      float pos = pp[qi] * nm1f;
      float lof = floorf(pos);
      float fr = pos - lof;
      int lo_i = (int)lof;
      int hi_i = min(lo_i + 1, last);
      bool needB = (fr > 0.0f) && (hi_i != lo_i);
      bool okA, okB = true; uint32_t beld;
      float va = wave_rank_value(t0 + (uint32_t)lo_i, HC1, G, LUT, s_roff, s_rcnt,
                                 HC2, HL3, lane, &st, &okA, &beld);
      float vb = va;
      if (needB)
        vb = wave_rank_value(t0 + (uint32_t)hi_i, HC1, G, LUT, s_roff, s_rcnt,
                             HC2, HL3, lane, &st, &okB, &beld);
      if (lane == 0) {
        s_qA[qi] = va; s_qB[qi] = vb; s_qfr[qi] = fr; s_qdup[qi] = needB ? 0 : 1;
        s_qfb[qi * 2]     = okA ? 0xFFFFFFFFu : (t0 + (uint32_t)lo_i);
        s_qfb[qi * 2 + 1] = (needB && !okB) ? (t0 + (uint32_t)hi_i) : 0xFFFFFFFFu;
      }
    }
  }
  __syncthreads();

  // ---- block-wide fallbacks for un-gathered quantile ranks (rare) ----
  for (int si = 0; si < 6; ++si) {
    uint32_t r = s_qfb[si];
    if (r != 0xFFFFFFFFu) {
      uint32_t bel;
      uint32_t key = global_select_key(sl, r, HC1, HC2, Wsum, &bel);
      if (tid == 0) {
        if (si & 1) s_qB[si >> 1] = key2f(key); else s_qA[si >> 1] = key2f(key);
      }
      __syncthreads();
    }
  }

  const float thresh = s_thresh;
  const uint32_t n = NPIX - s_cnlt;
  const float vmax  = key2f(smaxkey);
  const float vminf = thresh;

  // ---- Pass D (fused): masked moments, |x|, centroid, hist16, gradient ----
  float rng = vmax - vminf;
  float denomf = (rng > 0.0f) ? rng : 1.0f;
  float sxl = 0, sx2l = 0, sx3l = 0, sx4l = 0, sabl = 0, sgl = 0, sg2l = 0;
  uint32_t syi = 0, sxi = 0;
#pragma unroll 4
  for (int t = 0; t < EPT4; ++t) {
    int i4 = tid + t * NTHREADS;
    float4 v = sl4[i4];
    bool m0 = v.x >= thresh, m1 = v.y >= thresh, m2 = v.z >= thresh, m3 = v.w >= thresh;
    if (m0 | m1 | m2 | m3) {
      int y = i4 >> 6, xb = (i4 & 63) << 2;
      float4 up = sl4[(y > 0)   ? (i4 - 64) : i4];
      float4 dn = sl4[(y < 255) ? (i4 + 64) : i4];
      float lf = (xb > 0)   ? sl[4 * i4 - 1] : 0.0f;
      float rt = (xb < 252) ? sl[4 * i4 + 4] : 0.0f;
#define DOC(mc, vc, upc, dnc, lv, rv, xc)                                      \
      if (mc) {                                                                \
        float gy = (y == 0) ? (dnc - vc) : ((y == 255) ? (vc - upc) : 0.5f * (dnc - upc)); \
        int xx = xb + (xc);                                                    \
        float gx = (xx == 0) ? (rv - vc) : ((xx == 255) ? (vc - lv) : 0.5f * (rv - lv));   \
        float gm = sqrtf(gy * gy + gx * gx);                                   \
        sgl += gm; sg2l += gm * gm;                                            \
        float v2 = vc * vc;                                                    \
        sxl += vc; sx2l += v2; sx3l += v2 * vc; sx4l += v2 * v2;               \
        sabl += fabsf(vc);                                                     \
        syi += (uint32_t)y; sxi += (uint32_t)xx;                               \
        float bf = floorf((vc - vminf) / denomf * 16.0f);                      \
        int bin = (int)bf; bin = bin < 0 ? 0 : (bin > 15 ? 15 : bin);          \
        atomicAdd(&hist16[bin], 1u);                                           \
      }
      DOC(m0, v.x, up.x, dn.x, lf,  v.y, 0)
      DOC(m1, v.y, up.y, dn.y, v.x, v.z, 1)
      DOC(m2, v.z, up.z, dn.z, v.y, v.w, 2)
      DOC(m3, v.w, up.w, dn.w, v.z, rt,  3)
#undef DOC
    }
  }

  // ---- fused 9-way f64 reduction: per-wave shuffle, one barrier, wave-0 tree ----
  double a[9] = {(double)sxl, (double)sx2l, (double)sx3l, (double)sx4l,
                 (double)sabl, (double)sgl, (double)sg2l, (double)syi, (double)sxi};
#pragma unroll
  for (int k = 0; k < 9; ++k)
    for (int d = 32; d > 0; d >>= 1) a[k] += __shfl_down(a[k], d);
  if (lane == 0) {
#pragma unroll
    for (int k = 0; k < 9; ++k) tmpD9[wid * 9 + k] = a[k];
  }
  __syncthreads();
  if (tid < 64) {
    double r0 = 0, r1 = 0, r2 = 0, r3 = 0, r4 = 0, r5 = 0, r6 = 0, r7 = 0, r8 = 0;
    if (lane < 16) {
      r0 = tmpD9[lane * 9 + 0]; r1 = tmpD9[lane * 9 + 1]; r2 = tmpD9[lane * 9 + 2];
      r3 = tmpD9[lane * 9 + 3]; r4 = tmpD9[lane * 9 + 4]; r5 = tmpD9[lane * 9 + 5];
      r6 = tmpD9[lane * 9 + 6]; r7 = tmpD9[lane * 9 + 7]; r8 = tmpD9[lane * 9 + 8];
    }
    for (int d = 8; d > 0; d >>= 1) {
      r0 += __shfl_down(r0, d); r1 += __shfl_down(r1, d); r2 += __shfl_down(r2, d);
      r3 += __shfl_down(r3, d); r4 += __shfl_down(r4, d); r5 += __shfl_down(r5, d);
      r6 += __shfl_down(r6, d); r7 += __shfl_down(r7, d); r8 += __shfl_down(r8, d);
    }
    if (lane == 0) {
      s_red[0] = r0; s_red[1] = r1; s_red[2] = r2; s_red[3] = r3; s_red[4] = r4;
      s_red[5] = r5; s_red[6] = r6; s_red[7] = r7; s_red[8] = r8;
    }
  }
  __syncthreads();

  // ---- finalize features (thread 0) ----
  if (tid == 0) {
    double sx = s_red[0], sx2 = s_red[1], sx3 = s_red[2], sx4 = s_red[3];
    double sab = s_red[4], sg = s_red[5], sg2 = s_red[6], syid = s_red[7], sxid = s_red[8];
    double dn = (double)n;
    double mean = sx / dn;
    double M2 = sx2 - sx * sx / dn;
    double std_ = sqrt(M2 / dn);
    double se = fmax(std_, 1e-6);
    double S3 = sx3 - 3.0 * mean * sx2 + 2.0 * dn * mean * mean * mean;
    double S4 = sx4 - 4.0 * mean * sx3 + 6.0 * mean * mean * sx2
                - 3.0 * dn * mean * mean * mean * mean;
    double skew = (S3 / dn) / (se * se * se);
    skew = fmin(fmax(skew, -50.0), 50.0);
    double kurt = (S4 / dn) / (se * se * se * se);
    kurt = fmin(fmax(kurt, 0.0), 100.0);
    double msq = sx2 / dn;
    double absmean = sab / dn;

    double ent = 0.0;
    double nden = fmax(dn, 1.0);
    for (int bi = 0; bi < 16; ++bi) {
      double p = fmax((double)hist16[bi] / nden, 1e-6);
      ent -= p * log(p);
    }
    if (fabsf(vminf - vmax) <= 1e-8f + 1e-5f * fabsf(vmax)) ent = 0.0;

    double gmean = sg / dn;
    double gstd = sqrt(fmax(sg2 / dn - gmean * gmean, 0.0));
    double cy = (syid / dn) / 255.0;
    double cx = (sxid / dn) / 255.0;
    double frac = dn / (double)NPIX;

    float qv[3];
#pragma unroll
    for (int qi = 0; qi < 3; ++qi) {
      float A = s_qA[qi];
      float Bv = s_qdup[qi] ? A : s_qB[qi];
      float fr = s_qfr[qi];
      qv[qi] = A * (1.0f - fr) + Bv * fr;
    }

    float* fo = feats + (size_t)blockIdx.x * NFEAT;
    fo[0]  = (float)mean;  fo[1]  = (float)std_;  fo[2]  = vminf;       fo[3]  = vmax;
    fo[4]  = qv[0];        fo[5]  = qv[1];        fo[6]  = qv[2];       fo[7]  = (float)msq;
    fo[8]  = (float)ent;   fo[9]  = (float)skew;  fo[10] = (float)kurt; fo[11] = (float)frac;
    fo[12] = (float)gmean; fo[13] = (float)gstd;  fo[14] = (float)cy;   fo[15] = (float)cx;
    fo[16] = (float)frac;  fo[17] = (float)absmean;
  }
}

__global__ __launch_bounds__(EMB) void token_kernel(const float* __restrict__ feats,
                                                    const float* __restrict__ W,
                                                    const float* __restrict__ b,
                                                    const float* __restrict__ gamma,
                                                    const float* __restrict__ beta,
                                                    float* __restrict__ out,
                                                    float* __restrict__ maskout) {
  __shared__ float f[NFEAT];
  __shared__ float red[4];
  int s = blockIdx.x, e = threadIdx.x;
  if (e < NFEAT) f[e] = feats[(size_t)s * NFEAT + e];
  __syncthreads();
  float acc = b[e];
#pragma unroll
  for (int k = 0; k < NFEAT; ++k) acc += f[k] * W[k * EMB + e];
  int lane = e & 63, wd = e >> 6;
  float sum = acc;
  for (int d = 32; d > 0; d >>= 1) sum += __shfl_down(sum, d);
  if (lane == 0) red[wd] = sum;
  __syncthreads();
  float mu = (red[0] + red[1] + red[2] + red[3]) * (1.0f / EMB);
  float c = acc - mu;
  float s2 = c * c;
  for (int d = 32; d > 0; d >>= 1) s2 += __shfl_down(s2, d);
  __syncthreads();
  if (lane == 0) red[wd] = s2;
  __syncthreads();
  float var = (red[0] + red[1] + red[2] + red[3]) * (1.0f / EMB);
  float o = c / sqrtf(var + 1e-5f) * gamma[e] + beta[e];
  out[(size_t)s * EMB + e] = o;
  if (e == 0) maskout[s] = 0.0f;
}

extern "C" void kernel_launch(void* const* d_in, const int* in_sizes, int n_in,
                              void* d_out, int out_size, void* d_ws, size_t ws_size,
                              hipStream_t stream) {
  const float* vol   = (const float*)d_in[0];
  const float* W     = (const float*)d_in[1];
  const float* b     = (const float*)d_in[2];
  const float* gamma = (const float*)d_in[3];
  const float* beta  = (const float*)d_in[4];
  float* out = (float*)d_out;
  float* feats = (float*)d_ws;

  feat_kernel<<<NSLICES, NTHREADS, 0, stream>>>(vol, feats);
  token_kernel<<<NSLICES, EMB, 0, stream>>>(feats, W, b, gamma, beta,
                                            out, out + (size_t)NSLICES * EMB);
}